// Round 7
// baseline (943.942 us; speedup 1.0000x reference)
//
#include <hip/hip_runtime.h>
#include <stdint.h>

#define N_ROWS 12288
#define NPART_OFF (9437184 / 4)          // float offset of node partials in ws
#define EPART_OFF ((9437184 + 6291456) / 4)

typedef __attribute__((ext_vector_type(8))) short bf16x8;
typedef __attribute__((ext_vector_type(4))) float f32x4;

__device__ __forceinline__ uint32_t f2bf(float x) {
  union { float f; uint32_t u; } c; c.f = x;
  return (c.u + 0x7FFFu + ((c.u >> 16) & 1u)) >> 16;
}
__device__ __forceinline__ uint32_t pk_bf(float a, float b) {
  return f2bf(a) | (f2bf(b) << 16);
}
__device__ __forceinline__ uint32_t pk_pos(float a, float b) {
  return (a > 0.f ? 0x3F80u : 0u) | (b > 0.f ? 0x3F800000u : 0u);
}
__device__ __forceinline__ uint32_t pk_neg(float a, float b) {
  return (a < 0.f ? 0x3F80u : 0u) | (b < 0.f ? 0x3F800000u : 0u);
}

#define MFMA __builtin_amdgcn_mfma_f32_16x16x32_bf16

// ---------------------------------------------------------------------------
// Kernel 1: G_j = feats @ W_j (fp32), stored bf16 INTERLEAVED-TRANSPOSED:
//   cell(n, ko, j) = gt[((n*1536 + ko)*3 + j)*8 .. +8)   (ko = k/8, j = mat)
// so the 3 B-vectors for one (n, k-octet) are contiguous (one ptr + imm).
// ---------------------------------------------------------------------------
__global__ __launch_bounds__(256) void gw_kernel(
    const float* __restrict__ feats, const float* __restrict__ node_w,
    const float* __restrict__ edge_w, uint16_t* __restrict__ gt) {
  __shared__ float lf[16 * 128];
  const int t = threadIdx.x;
  const int kb = blockIdx.x * 16;
  {
    const float4* src = (const float4*)(feats + (size_t)kb * 128);
    float4* dst = (float4*)lf;
    dst[t] = src[t];
    dst[t + 256] = src[t + 256];
  }
  __syncthreads();
  const int n = t & 127;
  const int rh = t >> 7;
  const float* wb[3] = {node_w, node_w + 128 * 128, edge_w};
#pragma unroll
  for (int j = 0; j < 3; ++j) {
    const float* W = wb[j] + n;
    float acc[8];
#pragma unroll
    for (int q = 0; q < 8; ++q) acc[q] = 0.f;
    for (int i = 0; i < 128; i += 4) {
      const float w0 = W[(i + 0) * 128];
      const float w1 = W[(i + 1) * 128];
      const float w2 = W[(i + 2) * 128];
      const float w3 = W[(i + 3) * 128];
#pragma unroll
      for (int q = 0; q < 8; ++q) {
        const float4 f = *(const float4*)&lf[(rh * 8 + q) * 128 + i];
        acc[q] = fmaf(f.w, w3, fmaf(f.z, w2, fmaf(f.y, w1, fmaf(f.x, w0, acc[q]))));
      }
    }
    uint4 o;
    o.x = pk_bf(acc[0], acc[1]);
    o.y = pk_bf(acc[2], acc[3]);
    o.z = pk_bf(acc[4], acc[5]);
    o.w = pk_bf(acc[6], acc[7]);
    *(uint4*)(gt + ((size_t)(n * 1536 + (kb >> 3) + rh) * 3 + j) * 8) = o;
  }
}

// ---------------------------------------------------------------------------
// Kernel 2: producer/consumer wave specialization. 3072 blocks x 128 thr
// (wave 0 = producer, wave 1 = consumer). BM=32 rows, full 128 cols, BK=32,
// 8 K-slices of 1536 (slice = bid&7 = XCD -> gt slice 1.18MB L2-resident).
// Producer: HBM adjacency (2-deep ping/pong reg sets) -> pack bf16 -> LDS.
//   Its vmcnt FIFO holds ONLY HBM loads; counted waits, never drains.
// Consumer: ds_read 6 frags + B-loads from gt (pure-L2 vmcnt FIFO -- no
//   HBM poison possible) + 48 MFMA/iter. Raw s_barrier (no vmcnt drain).
// LDS: 2 bufs x [mat(3)][mf(2)][lane(64)][16B] = 12KB; stride-1 b128 ->
//   zero bank conflicts. ~8 waves/CU (VGPR ~210) = 4 blocks/CU, 3 rounds.
// ---------------------------------------------------------------------------
__global__ __launch_bounds__(128, 2) void fgc_main(
    const float* __restrict__ node_adj, const float* __restrict__ edge_adj,
    const uint16_t* __restrict__ gt, float* __restrict__ node_part,
    float* __restrict__ edge_part) {
  __shared__ __align__(128) char smem[12288];
  const int t = threadIdx.x;
  const int l = t & 63;
  const int bid = blockIdx.x;
  const int slice = bid & 7;
  const int row0 = (bid >> 3) * 32;
  const int k0 = slice * 1536;
  const int r15 = l & 15;
  const int gq = l >> 4;
  const int lo = l * 16;

  if (t < 64) {
    // ========================= producer wave =========================
    const float* nA = node_adj + (size_t)(row0 + r15) * N_ROWS + k0 + gq * 8;
    const float* nB = nA + (size_t)16 * N_ROWS;
    const float* eA = edge_adj + (size_t)(row0 + r15) * N_ROWS + k0 + gq * 8;
    const float* eB = eA + (size_t)16 * N_ROWS;

    float4 xa0, xa1, xb0, xb1, xc0, xc1, xd0, xd1;  // even kt
    float4 ya0, ya1, yb0, yb1, yc0, yc1, yd0, yd1;  // odd kt
    xa0 = *(const float4*)(nA);      xa1 = *(const float4*)(nA + 4);
    xb0 = *(const float4*)(nB);      xb1 = *(const float4*)(nB + 4);
    xc0 = *(const float4*)(eA);      xc1 = *(const float4*)(eA + 4);
    xd0 = *(const float4*)(eB);      xd1 = *(const float4*)(eB + 4);
    ya0 = *(const float4*)(nA + 32); ya1 = *(const float4*)(nA + 36);
    yb0 = *(const float4*)(nB + 32); yb1 = *(const float4*)(nB + 36);
    yc0 = *(const float4*)(eA + 32); yc1 = *(const float4*)(eA + 36);
    yd0 = *(const float4*)(eB + 32); yd1 = *(const float4*)(eB + 36);

#pragma unroll 1
    for (int kt = 0; kt < 48; kt += 2) {
      {  // pack + write X -> buf0
        char* wb = smem;
        uint4 P;
        P.x = pk_pos(xa0.x, xa0.y); P.y = pk_pos(xa0.z, xa0.w);
        P.z = pk_pos(xa1.x, xa1.y); P.w = pk_pos(xa1.z, xa1.w);
        *(uint4*)(wb + lo) = P;
        P.x = pk_pos(xb0.x, xb0.y); P.y = pk_pos(xb0.z, xb0.w);
        P.z = pk_pos(xb1.x, xb1.y); P.w = pk_pos(xb1.z, xb1.w);
        *(uint4*)(wb + 1024 + lo) = P;
        P.x = pk_neg(xa0.x, xa0.y); P.y = pk_neg(xa0.z, xa0.w);
        P.z = pk_neg(xa1.x, xa1.y); P.w = pk_neg(xa1.z, xa1.w);
        *(uint4*)(wb + 2048 + lo) = P;
        P.x = pk_neg(xb0.x, xb0.y); P.y = pk_neg(xb0.z, xb0.w);
        P.z = pk_neg(xb1.x, xb1.y); P.w = pk_neg(xb1.z, xb1.w);
        *(uint4*)(wb + 3072 + lo) = P;
        P.x = pk_bf(xc0.x, xc0.y);  P.y = pk_bf(xc0.z, xc0.w);
        P.z = pk_bf(xc1.x, xc1.y);  P.w = pk_bf(xc1.z, xc1.w);
        *(uint4*)(wb + 4096 + lo) = P;
        P.x = pk_bf(xd0.x, xd0.y);  P.y = pk_bf(xd0.z, xd0.w);
        P.z = pk_bf(xd1.x, xd1.y);  P.w = pk_bf(xd1.z, xd1.w);
        *(uint4*)(wb + 5120 + lo) = P;
      }
      if (kt + 2 < 48) {  // refill X with kt+2
        const int ko = (kt + 2) * 32;
        xa0 = *(const float4*)(nA + ko); xa1 = *(const float4*)(nA + ko + 4);
        xb0 = *(const float4*)(nB + ko); xb1 = *(const float4*)(nB + ko + 4);
        xc0 = *(const float4*)(eA + ko); xc1 = *(const float4*)(eA + ko + 4);
        xd0 = *(const float4*)(eB + ko); xd1 = *(const float4*)(eB + ko + 4);
      }
      asm volatile("s_waitcnt lgkmcnt(0)" ::: "memory");
      __builtin_amdgcn_s_barrier();

      {  // pack + write Y -> buf1
        char* wb = smem + 6144;
        uint4 P;
        P.x = pk_pos(ya0.x, ya0.y); P.y = pk_pos(ya0.z, ya0.w);
        P.z = pk_pos(ya1.x, ya1.y); P.w = pk_pos(ya1.z, ya1.w);
        *(uint4*)(wb + lo) = P;
        P.x = pk_pos(yb0.x, yb0.y); P.y = pk_pos(yb0.z, yb0.w);
        P.z = pk_pos(yb1.x, yb1.y); P.w = pk_pos(yb1.z, yb1.w);
        *(uint4*)(wb + 1024 + lo) = P;
        P.x = pk_neg(ya0.x, ya0.y); P.y = pk_neg(ya0.z, ya0.w);
        P.z = pk_neg(ya1.x, ya1.y); P.w = pk_neg(ya1.z, ya1.w);
        *(uint4*)(wb + 2048 + lo) = P;
        P.x = pk_neg(yb0.x, yb0.y); P.y = pk_neg(yb0.z, yb0.w);
        P.z = pk_neg(yb1.x, yb1.y); P.w = pk_neg(yb1.z, yb1.w);
        *(uint4*)(wb + 3072 + lo) = P;
        P.x = pk_bf(yc0.x, yc0.y);  P.y = pk_bf(yc0.z, yc0.w);
        P.z = pk_bf(yc1.x, yc1.y);  P.w = pk_bf(yc1.z, yc1.w);
        *(uint4*)(wb + 4096 + lo) = P;
        P.x = pk_bf(yd0.x, yd0.y);  P.y = pk_bf(yd0.z, yd0.w);
        P.z = pk_bf(yd1.x, yd1.y);  P.w = pk_bf(yd1.z, yd1.w);
        *(uint4*)(wb + 5120 + lo) = P;
      }
      if (kt + 3 < 48) {  // refill Y with kt+3
        const int ko = (kt + 3) * 32;
        ya0 = *(const float4*)(nA + ko); ya1 = *(const float4*)(nA + ko + 4);
        yb0 = *(const float4*)(nB + ko); yb1 = *(const float4*)(nB + ko + 4);
        yc0 = *(const float4*)(eA + ko); yc1 = *(const float4*)(eA + ko + 4);
        yd0 = *(const float4*)(eB + ko); yd1 = *(const float4*)(eB + ko + 4);
      }
      asm volatile("s_waitcnt lgkmcnt(0)" ::: "memory");
      __builtin_amdgcn_s_barrier();
    }
  } else {
    // ========================= consumer wave =========================
    const uint16_t* gB[8];
#pragma unroll
    for (int nf = 0; nf < 8; ++nf)
      gB[nf] = gt + (size_t)((nf * 16 + r15) * 1536 + (k0 >> 3) + gq) * 24;

    f32x4 accn[2][8], acce[2][8];
#pragma unroll
    for (int a = 0; a < 2; ++a)
#pragma unroll
      for (int b = 0; b < 8; ++b) {
        accn[a][b] = {0.f, 0.f, 0.f, 0.f};
        acce[a][b] = {0.f, 0.f, 0.f, 0.f};
      }

#pragma unroll 1
    for (int kt = 0; kt < 48; ++kt) {
      __builtin_amdgcn_s_barrier();
      const char* rb = smem + (kt & 1) * 6144;
      const bf16x8 pA = *(const bf16x8*)(rb + lo);
      const bf16x8 pB = *(const bf16x8*)(rb + 1024 + lo);
      const bf16x8 qA = *(const bf16x8*)(rb + 2048 + lo);
      const bf16x8 qB = *(const bf16x8*)(rb + 3072 + lo);
      const bf16x8 fA = *(const bf16x8*)(rb + 4096 + lo);
      const bf16x8 fB = *(const bf16x8*)(rb + 5120 + lo);
      const int kadv = kt * 96;
#pragma unroll
      for (int nf = 0; nf < 8; ++nf) {
        const uint16_t* gp = gB[nf] + kadv;
        const bf16x8 v1 = *(const bf16x8*)(gp);
        const bf16x8 v2 = *(const bf16x8*)(gp + 8);
        const bf16x8 v3 = *(const bf16x8*)(gp + 16);
        accn[0][nf] = MFMA(pA, v1, accn[0][nf], 0, 0, 0);
        accn[1][nf] = MFMA(pB, v1, accn[1][nf], 0, 0, 0);
        accn[0][nf] = MFMA(qA, v2, accn[0][nf], 0, 0, 0);
        accn[1][nf] = MFMA(qB, v2, accn[1][nf], 0, 0, 0);
        acce[0][nf] = MFMA(fA, v3, acce[0][nf], 0, 0, 0);
        acce[1][nf] = MFMA(fB, v3, acce[1][nf], 0, 0, 0);
      }
    }

    // epilogue: C/D frag row=(lane>>4)*4+q, col=lane&15
#pragma unroll
    for (int nf = 0; nf < 8; ++nf) {
      const int col = nf * 16 + r15;
#pragma unroll
      for (int mf = 0; mf < 2; ++mf) {
        const f32x4 nv = accn[mf][nf];
        const f32x4 ev = acce[mf][nf];
#pragma unroll
        for (int q = 0; q < 4; ++q) {
          const size_t idx = (size_t)(row0 + mf * 16 + gq * 4 + q) * 128 + col;
          unsafeAtomicAdd(&node_part[idx], nv[q]);
          unsafeAtomicAdd(&edge_part[idx], ev[q]);
        }
      }
    }
  }
}

// ---------------------------------------------------------------------------
// Kernel 3: out = relu(node_part + node_bias) + edge_part + edge_bias
// ---------------------------------------------------------------------------
__global__ __launch_bounds__(256) void fgc_final(
    const float* __restrict__ node_part, const float* __restrict__ edge_part,
    const float* __restrict__ node_bias, const float* __restrict__ edge_bias,
    float* __restrict__ out) {
  const int idx = blockIdx.x * 256 + threadIdx.x;  // one float4 each
  const int col = (idx * 4) & 127;
  const float4 n = ((const float4*)node_part)[idx];
  const float4 e = ((const float4*)edge_part)[idx];
  const float4 nb = *(const float4*)(node_bias + col);
  const float4 eb = *(const float4*)(edge_bias + col);
  float4 o;
  o.x = fmaxf(n.x + nb.x, 0.f) + e.x + eb.x;
  o.y = fmaxf(n.y + nb.y, 0.f) + e.y + eb.y;
  o.z = fmaxf(n.z + nb.z, 0.f) + e.z + eb.z;
  o.w = fmaxf(n.w + nb.w, 0.f) + e.w + eb.w;
  ((float4*)out)[idx] = o;
}

extern "C" void kernel_launch(void* const* d_in, const int* in_sizes, int n_in,
                              void* d_out, int out_size, void* d_ws, size_t ws_size,
                              hipStream_t stream) {
  const float* feats = (const float*)d_in[0];
  const float* node_adj = (const float*)d_in[1];
  const float* edge_adj = (const float*)d_in[2];
  const float* node_w = (const float*)d_in[3];
  const float* node_b = (const float*)d_in[4];
  const float* edge_w = (const float*)d_in[5];
  const float* edge_b = (const float*)d_in[6];
  uint16_t* gt = (uint16_t*)d_ws;                 // 9.44 MB
  float* node_part = (float*)d_ws + NPART_OFF;    // 6.29 MB
  float* edge_part = (float*)d_ws + EPART_OFF;    // 6.29 MB

  gw_kernel<<<768, 256, 0, stream>>>(feats, node_w, edge_w, gt);
  hipMemsetAsync((char*)d_ws + 9437184, 0, 2 * 6291456, stream);
  fgc_main<<<3072, 128, 0, stream>>>(node_adj, edge_adj, gt,
                                     node_part, edge_part);
  fgc_final<<<1536, 256, 0, stream>>>(node_part, edge_part, node_b, edge_b,
                                      (float*)d_out);
}

// Round 8
// 453.202 us; speedup vs baseline: 2.0828x; 2.0828x over previous
//
#include <hip/hip_runtime.h>
#include <stdint.h>

#define N_ROWS 12288
#define GSZ (128 * 12288)  // elements per G matrix (bf16)
#define NPART_OFF (9437184 / 4)          // float offset of node partials in ws
#define EPART_OFF ((9437184 + 6291456) / 4)

typedef __attribute__((ext_vector_type(8))) short bf16x8;
typedef __attribute__((ext_vector_type(4))) float f32x4;

__device__ __forceinline__ uint32_t f2bf(float x) {
  union { float f; uint32_t u; } c; c.f = x;
  return (c.u + 0x7FFFu + ((c.u >> 16) & 1u)) >> 16;
}
__device__ __forceinline__ uint32_t pk_bf(float a, float b) {
  return f2bf(a) | (f2bf(b) << 16);
}
__device__ __forceinline__ uint32_t pk_pos(float a, float b) {
  return (a > 0.f ? 0x3F80u : 0u) | (b > 0.f ? 0x3F800000u : 0u);
}
__device__ __forceinline__ uint32_t pk_neg(float a, float b) {
  return (a < 0.f ? 0x3F80u : 0u) | (b < 0.f ? 0x3F800000u : 0u);
}

#define MFMA __builtin_amdgcn_mfma_f32_16x16x32_bf16

// ---------------------------------------------------------------------------
// Kernel 1: G_j = feats @ W_j  (fp32), stored bf16 TRANSPOSED:
//   gt[j][n][k] = (feats @ W_j)[k][n]
// ---------------------------------------------------------------------------
__global__ __launch_bounds__(256) void gw_kernel(
    const float* __restrict__ feats, const float* __restrict__ node_w,
    const float* __restrict__ edge_w, uint16_t* __restrict__ gt) {
  __shared__ float lf[16 * 128];
  const int t = threadIdx.x;
  const int kb = blockIdx.x * 16;
  {
    const float4* src = (const float4*)(feats + (size_t)kb * 128);
    float4* dst = (float4*)lf;
    dst[t] = src[t];
    dst[t + 256] = src[t + 256];
  }
  __syncthreads();
  const int n = t & 127;
  const int rh = t >> 7;
  const float* wb[3] = {node_w, node_w + 128 * 128, edge_w};
#pragma unroll
  for (int j = 0; j < 3; ++j) {
    const float* W = wb[j] + n;
    float acc[8];
#pragma unroll
    for (int q = 0; q < 8; ++q) acc[q] = 0.f;
    for (int i = 0; i < 128; i += 4) {
      const float w0 = W[(i + 0) * 128];
      const float w1 = W[(i + 1) * 128];
      const float w2 = W[(i + 2) * 128];
      const float w3 = W[(i + 3) * 128];
#pragma unroll
      for (int q = 0; q < 8; ++q) {
        const float4 f = *(const float4*)&lf[(rh * 8 + q) * 128 + i];
        acc[q] = fmaf(f.w, w3, fmaf(f.z, w2, fmaf(f.y, w1, fmaf(f.x, w0, acc[q]))));
      }
    }
    uint4 ov;
    ov.x = pk_bf(acc[0], acc[1]);
    ov.y = pk_bf(acc[2], acc[3]);
    ov.z = pk_bf(acc[4], acc[5]);
    ov.w = pk_bf(acc[6], acc[7]);
    *(uint4*)(gt + (size_t)j * GSZ + (size_t)n * N_ROWS + kb + rh * 8) = ov;
  }
}

// ---------------------------------------------------------------------------
// Kernel 2: K-sliced partials. 1536 blocks x 512 thr (8 waves), 2 blocks/CU
// (VGPR<=128, LDS 24KB). BM=64, BK=32, 8 K-slices (slice=bid&7=XCD).
// Deep pipeline on the in-order vmcnt FIFO (steady-state issue order per
// half-iter kt): [pack X(kt) | lgkm+raw barrier | issue B(kt+1) |
// refill X(kt+2) | ds_read A + MFMA with B(kt) regs]. Every wait retires
// only data issued >=1 full iteration earlier (adjacency: 2 half-iters;
// B: 1 half-iter of L2 latency). No vmcnt(0) drain anywhere in the loop.
// Wave w owns cols [w*16, w*16+16): mf=4, nf=1.
// Staging: threads 0-255 stage node, 256-511 stage edge (wave-uniform).
// LDS: 2 bufs x (pos|neg|edge) x 64 rows x 32 bf16; granule swizzle
// p = g ^ ((row>>1)&3) -> 2-way (free) on both ds_write and ds_read_b128.
// ---------------------------------------------------------------------------
__global__ __launch_bounds__(512, 4) void fgc_main(
    const float* __restrict__ node_adj, const float* __restrict__ edge_adj,
    const uint16_t* __restrict__ gt, float* __restrict__ node_part,
    float* __restrict__ edge_part) {
  __shared__ __align__(128) char smem[24576];
  const int t = threadIdx.x;
  const int l = t & 63;
  const int w = t >> 6;  // 0..7
  const int bid = blockIdx.x;
  const int slice = bid & 7;
  const int row0 = (bid >> 3) * 64;
  const int k0 = slice * 1536;

  // staging: half-block per matrix; thread owns (row, 8-f32 granule)
  const int ts = t & 255;
  const int r = ts >> 2, o = ts & 3;
  const bool isNode = (t < 256);
  const float* src = (isNode ? node_adj : edge_adj) +
                     (size_t)(row0 + r) * N_ROWS + k0 + o * 8;
  const int wOff = r * 64 + ((o ^ ((r >> 1) & 3)) * 16);

  // A-frag read: row = mf*16 + r15, content granule gq
  const int r15 = l & 15;
  const int gq = l >> 4;
  const int abase = r15 * 64 + ((gq ^ ((r15 >> 1) & 3)) * 16);

  // B lane base: n = w*16 + r15, k = k0 + kt*32 + gq*8
  const uint16_t* gB = gt + (size_t)(w * 16 + r15) * N_ROWS + k0 + gq * 8;

  f32x4 accn[4], acce[4];
#pragma unroll
  for (int a = 0; a < 4; ++a) {
    accn[a] = {0.f, 0.f, 0.f, 0.f};
    acce[a] = {0.f, 0.f, 0.f, 0.f};
  }

  // prologue: adjacency sets X(kt=0), Y(kt=1); B set for kt=0
  float4 x0, x1, y0, y1;
  x0 = *(const float4*)(src);
  x1 = *(const float4*)(src + 4);
  y0 = *(const float4*)(src + 32);
  y1 = *(const float4*)(src + 36);
  bf16x8 bev1, bev2, bev3, bod1, bod2, bod3;
  bev1 = *(const bf16x8*)(gB);
  bev2 = *(const bf16x8*)(gB + GSZ);
  bev3 = *(const bf16x8*)(gB + 2 * GSZ);

#pragma unroll 1
  for (int k2 = 0; k2 < 24; ++k2) {
    const int kt = k2 * 2;
    // ================= even half: X -> buf0, compute kt =================
    if (isNode) {
      uint4 P, Q;
      P.x = pk_pos(x0.x, x0.y); P.y = pk_pos(x0.z, x0.w);
      P.z = pk_pos(x1.x, x1.y); P.w = pk_pos(x1.z, x1.w);
      Q.x = pk_neg(x0.x, x0.y); Q.y = pk_neg(x0.z, x0.w);
      Q.z = pk_neg(x1.x, x1.y); Q.w = pk_neg(x1.z, x1.w);
      *(uint4*)(smem + wOff) = P;
      *(uint4*)(smem + 4096 + wOff) = Q;
    } else {
      uint4 E;
      E.x = pk_bf(x0.x, x0.y); E.y = pk_bf(x0.z, x0.w);
      E.z = pk_bf(x1.x, x1.y); E.w = pk_bf(x1.z, x1.w);
      *(uint4*)(smem + 8192 + wOff) = E;
    }
    asm volatile("s_waitcnt lgkmcnt(0)" ::: "memory");
    __builtin_amdgcn_s_barrier();
    {  // issue B(kt+1) FIRST (older than the refill below)
      const uint16_t* gk = gB + (kt + 1) * 32;
      bod1 = *(const bf16x8*)(gk);
      bod2 = *(const bf16x8*)(gk + GSZ);
      bod3 = *(const bf16x8*)(gk + 2 * GSZ);
    }
    __builtin_amdgcn_sched_barrier(0);
    if (kt + 2 < 48) {  // refill X with adjacency(kt+2)
      const float* s2 = src + (kt + 2) * 32;
      x0 = *(const float4*)(s2);
      x1 = *(const float4*)(s2 + 4);
    }
    __builtin_amdgcn_sched_barrier(0);
    {  // compute kt from buf0 with B(kt) regs (arrived: issued last half)
      const char* rb = smem;
      bf16x8 ap[4], an[4], ae[4];
#pragma unroll
      for (int mf = 0; mf < 4; ++mf) {
        ap[mf] = *(const bf16x8*)(rb + abase + mf * 1024);
        an[mf] = *(const bf16x8*)(rb + 4096 + abase + mf * 1024);
        ae[mf] = *(const bf16x8*)(rb + 8192 + abase + mf * 1024);
      }
#pragma unroll
      for (int mf = 0; mf < 4; ++mf) {
        accn[mf] = MFMA(ap[mf], bev1, accn[mf], 0, 0, 0);
        accn[mf] = MFMA(an[mf], bev2, accn[mf], 0, 0, 0);
        acce[mf] = MFMA(ae[mf], bev3, acce[mf], 0, 0, 0);
      }
    }
    // ================= odd half: Y -> buf1, compute kt+1 =================
    if (isNode) {
      uint4 P, Q;
      P.x = pk_pos(y0.x, y0.y); P.y = pk_pos(y0.z, y0.w);
      P.z = pk_pos(y1.x, y1.y); P.w = pk_pos(y1.z, y1.w);
      Q.x = pk_neg(y0.x, y0.y); Q.y = pk_neg(y0.z, y0.w);
      Q.z = pk_neg(y1.x, y1.y); Q.w = pk_neg(y1.z, y1.w);
      *(uint4*)(smem + 12288 + wOff) = P;
      *(uint4*)(smem + 12288 + 4096 + wOff) = Q;
    } else {
      uint4 E;
      E.x = pk_bf(y0.x, y0.y); E.y = pk_bf(y0.z, y0.w);
      E.z = pk_bf(y1.x, y1.y); E.w = pk_bf(y1.z, y1.w);
      *(uint4*)(smem + 12288 + 8192 + wOff) = E;
    }
    asm volatile("s_waitcnt lgkmcnt(0)" ::: "memory");
    __builtin_amdgcn_s_barrier();
    if (kt + 2 < 48) {  // issue B(kt+2) FIRST
      const uint16_t* gk = gB + (kt + 2) * 32;
      bev1 = *(const bf16x8*)(gk);
      bev2 = *(const bf16x8*)(gk + GSZ);
      bev3 = *(const bf16x8*)(gk + 2 * GSZ);
    }
    __builtin_amdgcn_sched_barrier(0);
    if (kt + 3 < 48) {  // refill Y with adjacency(kt+3)
      const float* s3 = src + (kt + 3) * 32;
      y0 = *(const float4*)(s3);
      y1 = *(const float4*)(s3 + 4);
    }
    __builtin_amdgcn_sched_barrier(0);
    {  // compute kt+1 from buf1 with B(kt+1) regs
      const char* rb = smem + 12288;
      bf16x8 ap[4], an[4], ae[4];
#pragma unroll
      for (int mf = 0; mf < 4; ++mf) {
        ap[mf] = *(const bf16x8*)(rb + abase + mf * 1024);
        an[mf] = *(const bf16x8*)(rb + 4096 + abase + mf * 1024);
        ae[mf] = *(const bf16x8*)(rb + 8192 + abase + mf * 1024);
      }
#pragma unroll
      for (int mf = 0; mf < 4; ++mf) {
        accn[mf] = MFMA(ap[mf], bod1, accn[mf], 0, 0, 0);
        accn[mf] = MFMA(an[mf], bod2, accn[mf], 0, 0, 0);
        acce[mf] = MFMA(ae[mf], bod3, acce[mf], 0, 0, 0);
      }
    }
  }

  // accumulate partials: C/D frag row=(lane>>4)*4+q, col=lane&15
  const int col = w * 16 + r15;
#pragma unroll
  for (int mf = 0; mf < 4; ++mf) {
    const f32x4 nv = accn[mf];
    const f32x4 ev = acce[mf];
#pragma unroll
    for (int q = 0; q < 4; ++q) {
      const size_t idx = (size_t)(row0 + mf * 16 + gq * 4 + q) * 128 + col;
      unsafeAtomicAdd(&node_part[idx], nv[q]);
      unsafeAtomicAdd(&edge_part[idx], ev[q]);
    }
  }
}

// ---------------------------------------------------------------------------
// Kernel 3: out = relu(node_part + node_bias) + edge_part + edge_bias
// ---------------------------------------------------------------------------
__global__ __launch_bounds__(256) void fgc_final(
    const float* __restrict__ node_part, const float* __restrict__ edge_part,
    const float* __restrict__ node_bias, const float* __restrict__ edge_bias,
    float* __restrict__ out) {
  const int idx = blockIdx.x * 256 + threadIdx.x;  // one float4 each
  const int col = (idx * 4) & 127;
  const float4 n = ((const float4*)node_part)[idx];
  const float4 e = ((const float4*)edge_part)[idx];
  const float4 nb = *(const float4*)(node_bias + col);
  const float4 eb = *(const float4*)(edge_bias + col);
  float4 o;
  o.x = fmaxf(n.x + nb.x, 0.f) + e.x + eb.x;
  o.y = fmaxf(n.y + nb.y, 0.f) + e.y + eb.y;
  o.z = fmaxf(n.z + nb.z, 0.f) + e.z + eb.z;
  o.w = fmaxf(n.w + nb.w, 0.f) + e.w + eb.w;
  ((float4*)out)[idx] = o;
}

extern "C" void kernel_launch(void* const* d_in, const int* in_sizes, int n_in,
                              void* d_out, int out_size, void* d_ws, size_t ws_size,
                              hipStream_t stream) {
  const float* feats = (const float*)d_in[0];
  const float* node_adj = (const float*)d_in[1];
  const float* edge_adj = (const float*)d_in[2];
  const float* node_w = (const float*)d_in[3];
  const float* node_b = (const float*)d_in[4];
  const float* edge_w = (const float*)d_in[5];
  const float* edge_b = (const float*)d_in[6];
  uint16_t* gt = (uint16_t*)d_ws;                 // 9.44 MB
  float* node_part = (float*)d_ws + NPART_OFF;    // 6.29 MB
  float* edge_part = (float*)d_ws + EPART_OFF;    // 6.29 MB

  gw_kernel<<<768, 256, 0, stream>>>(feats, node_w, edge_w, gt);
  hipMemsetAsync((char*)d_ws + 9437184, 0, 2 * 6291456, stream);
  fgc_main<<<1536, 512, 0, stream>>>(node_adj, edge_adj, gt,
                                     node_part, edge_part);
  fgc_final<<<1536, 256, 0, stream>>>(node_part, edge_part, node_b, edge_b,
                                      (float*)d_out);
}